// Round 1
// baseline (475.643 us; speedup 1.0000x reference)
//
#include <hip/hip_runtime.h>
#include <hip/hip_fp16.h>
#include <stdint.h>

// Problem constants
#define TS     200     // SEQLEN / OSC_TIME
#define NB     32      // BATCH
#define NU     256     // UNITS
#define ND     256     // D_IN

typedef _Float16 h2_t __attribute__((ext_vector_type(2)));

static __device__ __forceinline__ float fdot2f(uint32_t w, uint32_t h, float acc) {
#if __has_builtin(__builtin_amdgcn_fdot2)
    return __builtin_amdgcn_fdot2(__builtin_bit_cast(h2_t, w),
                                  __builtin_bit_cast(h2_t, h), acc, false);
#else
    h2_t a = __builtin_bit_cast(h2_t, w), b = __builtin_bit_cast(h2_t, h);
    acc = fmaf((float)a.x, (float)b.x, acc);
    acc = fmaf((float)a.y, (float)b.y, acc);
    return acc;
#endif
}

// ---------------------------------------------------------------------------
// K0: pack W_h (fp32 [4][2][256][256]) -> half2 pairs, layout
// Wp[c][g][vblk=32][u=256][j=4]  (uint per (2 v's, u)); uint4-read friendly.
// ---------------------------------------------------------------------------
__global__ void pack_wh(const float* __restrict__ Wh, uint32_t* __restrict__ Wp) {
    int idx = blockIdx.x * 256 + threadIdx.x;       // 4*2*32*256*4 = 262144
    if (idx >= 4 * 2 * 32 * 256 * 4) return;
    int j    = idx & 3;
    int u    = (idx >> 2) & 255;
    int vblk = (idx >> 10) & 31;
    int g    = (idx >> 15) & 1;
    int c    = idx >> 16;
    int v    = vblk * 8 + j * 2;
    const float* base = Wh + ((size_t)((c * 2 + g) * 256 + v)) * 256 + u;
    h2_t p;
    p.x = (_Float16)base[0];      // W[v]
    p.y = (_Float16)base[256];    // W[v+1]
    Wp[idx] = __builtin_bit_cast(uint32_t, p);
}

// ---------------------------------------------------------------------------
// K1: xp[c][b][t][g][u] = sum_d x[b][10t][d] * Wx[c][g][d][u] + bx[c][g][u]
// fp32 LDS-tiled 64x64 GEMM, K=256 in 8 stages of 32.
// Grid: (ntile=8, mtile=100, c=4), block 256.
// ---------------------------------------------------------------------------
__device__ __forceinline__ void store4(float* p, float4 v) { *(float4*)p = v; }
__device__ __forceinline__ void store4(_Float16* p, float4 v) {
    h2_t a, b; a.x = (_Float16)v.x; a.y = (_Float16)v.y;
    b.x = (_Float16)v.z; b.y = (_Float16)v.w;
    uint2 t; t.x = __builtin_bit_cast(uint32_t, a); t.y = __builtin_bit_cast(uint32_t, b);
    *(uint2*)p = t;
}

template <typename XT>
__global__ __launch_bounds__(256) void xp_gemm(const float* __restrict__ x,
                                               const float* __restrict__ Wx,
                                               const float* __restrict__ bx,
                                               XT* __restrict__ xp) {
    const int c   = blockIdx.z;
    const int m0  = blockIdx.y * 64;       // row = b*200 + t
    const int n0  = blockIdx.x * 64;       // col in [0,512) = (g,u)
    const int g   = n0 >> 8;
    const int u0g = n0 & 255;

    __shared__ float As[64][36];           // [m][k], stride 36 (16B-aligned rows)
    __shared__ float Bs[64][38];           // [n][k], stride 38 (2-way max conflicts)

    const int tid = threadIdx.x;
    const int tm = tid >> 4, tn = tid & 15;

    // A loader: ar in [0,64), 8 consecutive k's
    const int ar = tid >> 2, ac = (tid & 3) * 8;
    const int am = m0 + ar;
    const int ab = am / 200, at = am % 200;
    const float* aptr = x + ((size_t)(ab * 2000 + at * 10)) * 256 + ac;

    // B loader: 2 k-rows x 4 u's
    const int bk2 = tid >> 4, bn = (tid & 15) * 4;
    const float* bptr = Wx + ((size_t)((c * 2 + g) * 256 + 2 * bk2)) * 256 + u0g + bn;

    float2 acc[4][4];
#pragma unroll
    for (int i = 0; i < 4; i++)
#pragma unroll
        for (int j = 0; j < 4; j++) acc[i][j] = make_float2(0.f, 0.f);

    for (int s = 0; s < 8; s++) {
        const int k0 = s * 32;
        float4 a0  = *(const float4*)(aptr + k0);
        float4 a1  = *(const float4*)(aptr + k0 + 4);
        float4 blo = *(const float4*)(bptr + (size_t)k0 * 256);
        float4 bhi = *(const float4*)(bptr + (size_t)(k0 + 1) * 256);
        __syncthreads();   // previous stage's LDS reads complete
        store4(&As[ar][ac], a0);
        store4(&As[ar][ac + 4], a1);
        // k-major B: Bs[n][k]
        *(float2*)&Bs[bn + 0][2 * bk2] = make_float2(blo.x, bhi.x);
        *(float2*)&Bs[bn + 1][2 * bk2] = make_float2(blo.y, bhi.y);
        *(float2*)&Bs[bn + 2][2 * bk2] = make_float2(blo.z, bhi.z);
        *(float2*)&Bs[bn + 3][2 * bk2] = make_float2(blo.w, bhi.w);
        __syncthreads();
#pragma unroll
        for (int k2 = 0; k2 < 16; k2++) {
            float2 a2[4], b2[4];
#pragma unroll
            for (int i = 0; i < 4; i++) a2[i] = *(const float2*)&As[tm * 4 + i][2 * k2];
#pragma unroll
            for (int j = 0; j < 4; j++) b2[j] = *(const float2*)&Bs[tn * 4 + j][2 * k2];
#pragma unroll
            for (int i = 0; i < 4; i++)
#pragma unroll
                for (int j = 0; j < 4; j++) {
                    acc[i][j].x = fmaf(a2[i].x, b2[j].x, acc[i][j].x);
                    acc[i][j].y = fmaf(a2[i].y, b2[j].y, acc[i][j].y);
                }
        }
    }

    // epilogue: xp[c][b][t][g][u], u block of 4 contiguous
#pragma unroll
    for (int i = 0; i < 4; i++) {
        int m = m0 + tm * 4 + i;
        int b = m / 200, t = m % 200;
        float4 res;
        res.x = acc[i][0].x + acc[i][0].y + bx[(c * 2 + g) * 256 + u0g + tn * 4 + 0];
        res.y = acc[i][1].x + acc[i][1].y + bx[(c * 2 + g) * 256 + u0g + tn * 4 + 1];
        res.z = acc[i][2].x + acc[i][2].y + bx[(c * 2 + g) * 256 + u0g + tn * 4 + 2];
        res.w = acc[i][3].x + acc[i][3].y + bx[(c * 2 + g) * 256 + u0g + tn * 4 + 3];
        size_t off = ((size_t)((c * 32 + b) * 200 + t) * 2 + g) * 256 + u0g + tn * 4;
        store4(xp + off, res);
    }
}

// ---------------------------------------------------------------------------
// K2: the 200-step gated recurrence. One WG per (c,b): 128 WGs x 1024 threads.
// thread = (u:256, g:2, vh:2). W_h fragment register-resident as fp16 pairs
// (64 VGPRs), h state fp32 in thread u's register, fp16-packed copy in LDS
// for the dot (v_dot2_f32_f16, fp32 accumulate).
// hs[c][b][t][u] written fp32 for phase 3.
// ---------------------------------------------------------------------------
template <typename XT>
__global__ __launch_bounds__(1024, 4) void recurrence(const XT* __restrict__ xp,
                                                      const float* __restrict__ bh,
                                                      const uint4* __restrict__ Wp,
                                                      float* __restrict__ hs) {
    const int c = blockIdx.x >> 5;
    const int b = blockIdx.x & 31;
    const int tid = threadIdx.x;
    const int u  = tid & 255;
    const int g  = (tid >> 8) & 1;
    const int vh = tid >> 9;             // 0/1 -> v in [vh*128, vh*128+128)

    __shared__ __align__(16) uint32_t h2s[128];     // h packed as 128 half2 pairs
    __shared__ float partial[2][2][256];            // [g][vh][u]
    __shared__ float sg[2][256];                    // sigmoid outputs [g][u]

    // register-resident weight fragment: 16 x uint4 = 64 half2 = 128 v's
    uint4 w[16];
    const uint4* wbase = Wp + ((size_t)((c * 2 + g) * 32 + vh * 16)) * 256 + u;
#pragma unroll
    for (int i = 0; i < 16; i++) w[i] = wbase[(size_t)i * 256];

    float bias = 0.f;
    const XT* xpb = nullptr;
    if (tid < 512) {
        bias = bh[(c * 2 + g) * 256 + u];
        xpb  = xp + ((size_t)((c * 32 + b) * 200) * 2 + g) * 256 + u;
    }
    float hreg = 0.f;                    // thread u (< 256) owns h[u]

    if (tid < 128) h2s[tid] = 0u;        // h0 = 0
    __syncthreads();

    const size_t hs_base = (size_t)((c * 32 + b) * 200) * 256 + u;

    for (int t = 0; t < TS; t++) {
        float xpv = 0.f;
        if (tid < 512) xpv = (float)xpb[(size_t)t * 512];   // prefetch, used post-dot

        // dot over our 128 v's: 16 x (b128 LDS broadcast + 4 fdot2)
        float acc = 0.f;
#pragma unroll
        for (int i = 0; i < 16; i++) {
            uint4 hh = *(const uint4*)(h2s + vh * 64 + i * 4);
            acc = fdot2f(w[i].x, hh.x, acc);
            acc = fdot2f(w[i].y, hh.y, acc);
            acc = fdot2f(w[i].z, hh.z, acc);
            acc = fdot2f(w[i].w, hh.w, acc);
        }
        partial[g][vh][u] = acc;
        __syncthreads();

        if (tid < 512) {
            float s = partial[g][0][u] + partial[g][1][u] + xpv + bias;
            sg[g][u] = 1.f / (1.f + __expf(-s));
        }
        __syncthreads();

        if (tid < 256) {
            float j = sg[0][u], k = sg[1][u];
            float hn = j + hreg * (1.f - j - k);    // j*(1-h) + (1-k)*h
            hreg = hn;
            hs[hs_base + (size_t)t * 256] = hn;
            float other = __shfl_xor(hn, 1);
            if ((u & 1) == 0) {
                h2_t p; p.x = (_Float16)hn; p.y = (_Float16)other;
                h2s[u >> 1] = __builtin_bit_cast(uint32_t, p);
            }
        }
        __syncthreads();
    }
}

// ---------------------------------------------------------------------------
// K3: oscillator expansion. thread = (b,t,u); 10 sequential steps in regs.
// out[b][t*10+s][u] = r_s * cos(phi_s)
// ---------------------------------------------------------------------------
__global__ __launch_bounds__(256) void osc(const float* __restrict__ hs,
                                           float* __restrict__ out) {
    int tid = blockIdx.x * 256 + threadIdx.x;   // 32*200*256 = 1,638,400
    const int cstride = 32 * 200 * 256;
    int u  = tid & 255;
    int bt = tid >> 8;
    int t = bt % 200, b = bt / 200;
    float phi   = hs[0 * cstride + tid];
    float omega = hs[1 * cstride + tid];
    float r     = hs[2 * cstride + tid];
    float mu    = hs[3 * cstride + tid];
    float* o = out + ((size_t)(b * 2000 + t * 10)) * 256 + u;
#pragma unroll
    for (int s = 0; s < 10; s++) {
        o[(size_t)s * 256] = r * __cosf(phi);
        r = r + (mu - r * r) * r;
        phi = phi + omega;
    }
}

// ---------------------------------------------------------------------------
extern "C" void kernel_launch(void* const* d_in, const int* in_sizes, int n_in,
                              void* d_out, int out_size, void* d_ws, size_t ws_size,
                              hipStream_t stream) {
    const float* x  = (const float*)d_in[0];
    const float* Wx = (const float*)d_in[1];
    const float* bx = (const float*)d_in[2];
    const float* Wh = (const float*)d_in[3];
    const float* bh = (const float*)d_in[4];
    float* out = (float*)d_out;

    char* ws = (char*)d_ws;
    const size_t xp_f32 = (size_t)4 * 32 * 200 * 2 * 256 * 4;   // 52.4 MB
    const size_t hs_b   = (size_t)4 * 32 * 200 * 256 * 4;       // 26.2 MB
    const size_t wp_b   = (size_t)4 * 2 * 32 * 256 * 16;        // 1 MB
    // prefer fp32 xp; fall back to fp16 xp if workspace is tight
    bool xp_half = ws_size < (xp_f32 + hs_b + wp_b);
    size_t xp_bytes = xp_half ? xp_f32 / 2 : xp_f32;
    void*  xp = (void*)ws;
    float* hs = (float*)(ws + xp_bytes);
    uint4* Wp = (uint4*)(ws + xp_bytes + hs_b);

    pack_wh<<<1024, 256, 0, stream>>>(Wh, (uint32_t*)Wp);
    if (!xp_half) {
        xp_gemm<float><<<dim3(8, 100, 4), 256, 0, stream>>>(x, Wx, bx, (float*)xp);
        recurrence<float><<<128, 1024, 0, stream>>>((const float*)xp, bh, Wp, hs);
    } else {
        xp_gemm<_Float16><<<dim3(8, 100, 4), 256, 0, stream>>>(x, Wx, bx, (_Float16*)xp);
        recurrence<_Float16><<<128, 1024, 0, stream>>>((const _Float16*)xp, bh, Wp, hs);
    }
    osc<<<6400, 256, 0, stream>>>(hs, out);
}

// Round 2
// 382.353 us; speedup vs baseline: 1.2440x; 1.2440x over previous
//
#include <hip/hip_runtime.h>
#include <hip/hip_fp16.h>
#include <stdint.h>

#define TS 200

typedef _Float16 h2_t  __attribute__((ext_vector_type(2)));
typedef _Float16 f16x8 __attribute__((ext_vector_type(8)));
typedef float    f32x4 __attribute__((ext_vector_type(4)));

static __device__ __forceinline__ float fdot2f(uint32_t w, uint32_t h, float acc) {
#if __has_builtin(__builtin_amdgcn_fdot2)
    return __builtin_amdgcn_fdot2(__builtin_bit_cast(h2_t, w),
                                  __builtin_bit_cast(h2_t, h), acc, false);
#else
    h2_t a = __builtin_bit_cast(h2_t, w), b = __builtin_bit_cast(h2_t, h);
    acc = fmaf((float)a.x, (float)b.x, acc);
    acc = fmaf((float)a.y, (float)b.y, acc);
    return acc;
#endif
}

// DPP add-reduce helper: acc += dpp_move(acc). All lanes active when called.
template <int CTRL>
static __device__ __forceinline__ float dpp_add(float x) {
    int m = __builtin_amdgcn_update_dpp(0, __builtin_bit_cast(int, x), CTRL, 0xF, 0xF, true);
    return x + __builtin_bit_cast(float, m);
}

// ---------------------------------------------------------------------------
// K0: one-time packs.
//  blocks [0,6400):        xh[row=b*200+t][k] = f16(x[b][10t][k])
//  blocks [6400,8448):     wxt[n=c*512+g*256+u][k] = f16(Wx[c][g][k][u])
//  blocks [8448,9472):     wp: W_h fp16 pairs in recurrence thread layout
//                          [c][g][j=16][thr=512][e=4] (uint per (2v,u))
// ---------------------------------------------------------------------------
__global__ __launch_bounds__(256) void pack_all(const float* __restrict__ x,
                                                const float* __restrict__ Wx,
                                                const float* __restrict__ Wh,
                                                _Float16* __restrict__ xh,
                                                _Float16* __restrict__ wxt,
                                                uint32_t* __restrict__ wp) {
    int bid = blockIdx.x, tid = threadIdx.x;
    if (bid < 6400) {
        int row = bid, col = tid;
        int b = row / 200, t = row - b * 200;
        xh[(size_t)row * 256 + col] = (_Float16)x[((size_t)(b * 2000 + t * 10)) * 256 + col];
    } else if (bid < 8448) {
        int n = bid - 6400, k = tid;
        wxt[(size_t)n * 256 + k] = (_Float16)Wx[((size_t)((n >> 8) * 256 + k)) * 256 + (n & 255)];
    } else {
        int idx = (bid - 8448) * 256 + tid;          // [0, 262144)
        int e = idx & 3, thr = (idx >> 2) & 511, j = (idx >> 11) & 15;
        int g = (idx >> 15) & 1, c = idx >> 16;
        int vs = thr & 7, uq = (thr >> 3) & 7, wu = thr >> 6;
        int uu = j >> 2, i = j & 3;
        int u = wu * 32 + uq * 4 + uu;
        int v = vs * 32 + i * 8 + e * 2;
        const float* base = Wh + ((size_t)((c * 2 + g) * 256 + v)) * 256 + u;
        h2_t p; p.x = (_Float16)base[0]; p.y = (_Float16)base[256];
        wp[idx] = __builtin_bit_cast(uint32_t, p);
    }
}

// ---------------------------------------------------------------------------
// K1: xp = X[6400x256] * W[256x2048] + bias, f16 MFMA 16x16x32.
// 128x128 tile, BK=64, 4 waves (each a 64x64 quadrant, 4x4 16x16 tiles).
// Staging via global_load_lds width=16 (lane l -> lds base + 16*l).
// Output xp f16 [cb][t][g*256+u].
// ---------------------------------------------------------------------------
__global__ __launch_bounds__(256) void xp_gemm(const _Float16* __restrict__ xh,
                                               const _Float16* __restrict__ wxt,
                                               const float* __restrict__ bxf,
                                               _Float16* __restrict__ xp) {
    __shared__ _Float16 As[128 * 64];
    __shared__ _Float16 Bs[128 * 64];
    const int tid = threadIdx.x;
    const int lane = tid & 63, w = tid >> 6;
    const int m0 = (blockIdx.x >> 4) * 128;
    const int n0 = (blockIdx.x & 15) * 128;
    const int mw = (w & 1) * 64, nw = (w >> 1) * 64;

    f32x4 acc[4][4] = {};

    for (int kb = 0; kb < 4; kb++) {
        const int k0 = kb * 64;
#pragma unroll
        for (int q = 0; q < 4; q++) {
            int ii = w * 4 + q;                       // 0..15 chunk id
            int r = ii * 8 + (lane >> 3);             // row 0..127
            int kcol = (lane & 7) * 8;
            const _Float16* ga = xh  + (size_t)(m0 + r) * 256 + k0 + kcol;
            const _Float16* gb = wxt + (size_t)(n0 + r) * 256 + k0 + kcol;
            __builtin_amdgcn_global_load_lds(
                (const __attribute__((address_space(1))) uint32_t*)ga,
                (__attribute__((address_space(3))) uint32_t*)(As + ii * 512), 16, 0, 0);
            __builtin_amdgcn_global_load_lds(
                (const __attribute__((address_space(1))) uint32_t*)gb,
                (__attribute__((address_space(3))) uint32_t*)(Bs + ii * 512), 16, 0, 0);
        }
        __syncthreads();
#pragma unroll
        for (int kc = 0; kc < 2; kc++) {
            f16x8 a[4], b[4];
#pragma unroll
            for (int mt = 0; mt < 4; mt++)
                a[mt] = *(const f16x8*)&As[(mw + mt * 16 + (lane & 15)) * 64 + kc * 32 + (lane >> 4) * 8];
#pragma unroll
            for (int nt = 0; nt < 4; nt++)
                b[nt] = *(const f16x8*)&Bs[(nw + nt * 16 + (lane & 15)) * 64 + kc * 32 + (lane >> 4) * 8];
#pragma unroll
            for (int mt = 0; mt < 4; mt++)
#pragma unroll
                for (int nt = 0; nt < 4; nt++)
                    acc[mt][nt] = __builtin_amdgcn_mfma_f32_16x16x32_f16(a[mt], b[nt], acc[mt][nt], 0, 0, 0);
        }
        __syncthreads();
    }

    const int nl = lane & 15, quad = lane >> 4;
#pragma unroll
    for (int nt = 0; nt < 4; nt++) {
        int n = n0 + nw + nt * 16 + nl;
        float bias = bxf[n];
        int c = n >> 9, gu = n & 511;
#pragma unroll
        for (int mt = 0; mt < 4; mt++)
#pragma unroll
            for (int r = 0; r < 4; r++) {
                int m = m0 + mw + mt * 16 + quad * 4 + r;
                int b = m / 200, t = m - b * 200;
                xp[((size_t)((c * 32 + b) * 200 + t)) * 512 + gu] =
                    (_Float16)(acc[mt][nt][r] + bias);
            }
    }
}

// ---------------------------------------------------------------------------
// K2: 200-step gated recurrence. 128 WGs (c,b) x 1024 threads.
// Thread (g = tid>>9, wave-u wu, u-quad uq, v-slice vs): 4 u's x 32 v's.
// h delivered by ONE conflict-free b128 LDS read per 16 fdot2 (u_per=4);
// cross-vs reduction entirely in VALU via DPP (xor1, xor2, l^7 mirror).
// ---------------------------------------------------------------------------
__global__ __launch_bounds__(1024, 4) void recurrence(const _Float16* __restrict__ xp,
                                                      const float* __restrict__ bh,
                                                      const uint32_t* __restrict__ Wp,
                                                      float* __restrict__ hs) {
    const int c = blockIdx.x >> 5;
    const int b = blockIdx.x & 31;
    const int tid = threadIdx.x;
    const int g = tid >> 9;
    const int thr = tid & 511;
    const int lane = tid & 63;
    const int vs = lane & 7;
    const int uq = lane >> 3;
    const int wu = (tid >> 6) & 7;

    __shared__ __align__(16) uint32_t h2s[8 * 20];   // 8 v-slices x 16 uints + 4 pad
    __shared__ float sg[512];                        // [u][g] sigmoid outputs

    // register-resident weights: 16 uint4 = 64 half2 (4 u's x 32 v's)
    uint4 w[16];
    {
        const uint4* wb = (const uint4*)Wp + ((size_t)(c * 2 + g) * 16) * 512 + thr;
#pragma unroll
        for (int j = 0; j < 16; j++) w[j] = wb[(size_t)j * 512];
    }

    const int u_w = wu * 32 + uq * 4 + vs;           // writer u (valid when vs<4)
    float bias = 0.f;
    const _Float16* xpb = nullptr;
    if (vs < 4) {
        bias = bh[(c * 2 + g) * 256 + u_w];
        xpb = xp + ((size_t)((c * 32 + b) * 200)) * 512 + g * 256 + u_w;
    }

    float hreg = 0.f;                                // thread tid<256 owns h[tid]
    if (tid < 160) h2s[tid] = 0u;
    __syncthreads();

    const size_t hsb = (size_t)((c * 32 + b) * 200) * 256 + tid;

    for (int t = 0; t < TS; t++) {
        float xpv = 0.f;
        if (vs < 4) xpv = (float)xpb[(size_t)t * 512];

        uint4 hh[4];
#pragma unroll
        for (int i = 0; i < 4; i++) hh[i] = *(const uint4*)(h2s + vs * 20 + i * 4);

        float acc[4] = {0.f, 0.f, 0.f, 0.f};
#pragma unroll
        for (int uu = 0; uu < 4; uu++)
#pragma unroll
            for (int i = 0; i < 4; i++) {
                acc[uu] = fdot2f(w[uu * 4 + i].x, hh[i].x, acc[uu]);
                acc[uu] = fdot2f(w[uu * 4 + i].y, hh[i].y, acc[uu]);
                acc[uu] = fdot2f(w[uu * 4 + i].z, hh[i].z, acc[uu]);
                acc[uu] = fdot2f(w[uu * 4 + i].w, hh[i].w, acc[uu]);
            }
#pragma unroll
        for (int uu = 0; uu < 4; uu++) {
            float a = acc[uu];
            a = dpp_add<0xB1>(a);    // quad_perm xor1
            a = dpp_add<0x4E>(a);    // quad_perm xor2
            a = dpp_add<0x141>(a);   // row_half_mirror: l ^ 7 within 8
            acc[uu] = a;
        }
        if (vs < 4) {
            float s = (vs == 0 ? acc[0] : vs == 1 ? acc[1] : vs == 2 ? acc[2] : acc[3])
                      + xpv + bias;
            sg[u_w * 2 + g] = 1.f / (1.f + __expf(-s));
        }
        __syncthreads();
        if (tid < 256) {
            float2 jk = *(const float2*)(sg + tid * 2);
            float hn = jk.x + hreg * (1.f - jk.x - jk.y);
            hreg = hn;
            hs[hsb + (size_t)t * 256] = hn;
            ((_Float16*)h2s)[(tid >> 5) * 40 + (tid & 31)] = (_Float16)hn;
        }
        __syncthreads();
    }
}

// ---------------------------------------------------------------------------
// K3: oscillator expansion (memory-bound).
// ---------------------------------------------------------------------------
__global__ __launch_bounds__(256) void osc(const float* __restrict__ hs,
                                           float* __restrict__ out) {
    int tid = blockIdx.x * 256 + threadIdx.x;   // 1,638,400
    const int cstride = 32 * 200 * 256;
    int u = tid & 255;
    int bt = tid >> 8;
    int t = bt % 200, b = bt / 200;
    float phi   = hs[0 * cstride + tid];
    float omega = hs[1 * cstride + tid];
    float r     = hs[2 * cstride + tid];
    float mu    = hs[3 * cstride + tid];
    float* o = out + ((size_t)(b * 2000 + t * 10)) * 256 + u;
#pragma unroll
    for (int s = 0; s < 10; s++) {
        o[(size_t)s * 256] = r * __cosf(phi);
        r = r + (mu - r * r) * r;
        phi = phi + omega;
    }
}

// ---------------------------------------------------------------------------
extern "C" void kernel_launch(void* const* d_in, const int* in_sizes, int n_in,
                              void* d_out, int out_size, void* d_ws, size_t ws_size,
                              hipStream_t stream) {
    const float* x  = (const float*)d_in[0];
    const float* Wx = (const float*)d_in[1];
    const float* bx = (const float*)d_in[2];
    const float* Wh = (const float*)d_in[3];
    const float* bh = (const float*)d_in[4];
    float* out = (float*)d_out;

    char* ws = (char*)d_ws;
    const size_t XP = (size_t)4 * 32 * 200 * 512 * 2;   // 26.2 MB f16
    const size_t HS = (size_t)4 * 32 * 200 * 256 * 4;   // 26.2 MB f32
    const size_t XH = (size_t)6400 * 256 * 2;           // 3.28 MB

    _Float16* xp  = (_Float16*)ws;
    float*    hs  = (float*)(ws + XP);
    // xh/wxt alias the hs region: they are dead before recurrence writes hs.
    _Float16* xh  = (_Float16*)(ws + XP);
    _Float16* wxt = (_Float16*)(ws + XP + XH);
    uint32_t* wp  = (uint32_t*)(ws + XP + HS);

    pack_all<<<9472, 256, 0, stream>>>(x, Wx, Wh, xh, wxt, wp);
    xp_gemm<<<800, 256, 0, stream>>>(xh, wxt, bx, xp);
    recurrence<<<128, 1024, 0, stream>>>(xp, bh, wp, hs);
    osc<<<6400, 256, 0, stream>>>(hs, out);
}